// Round 15
// baseline (1135.592 us; speedup 1.0000x reference)
//
#include <hip/hip_runtime.h>
#include <hip/hip_bf16.h>
#include <math.h>

#define NTOK 196
#define KPAD 224
#define BATCH 32
#define ROWS (BATCH * NTOK)   // 6272
#define DIMC 768
#define MLPD 3072

typedef __hip_bfloat16 bf16;
typedef short bf16x8 __attribute__((ext_vector_type(8)));
typedef float f32x4 __attribute__((ext_vector_type(4)));

__device__ __forceinline__ void gload16(const void* g, void* l) {
    __builtin_amdgcn_global_load_lds(
        (__attribute__((address_space(1))) void*)const_cast<void*>(g),
        (__attribute__((address_space(3))) void*)l, 16, 0, 0);
}

__device__ __forceinline__ float softplus_f(float x) {
    return fmaxf(x, 0.f) + log1pf(expf(-fabsf(x)));
}
__device__ __forceinline__ float gelu_f(float x) {
    return 0.5f * x * (1.f + erff(x * 0.70710678118654752f));
}
__device__ __forceinline__ float to_f(float x) { return x; }
__device__ __forceinline__ float to_f(bf16 x) { return __bfloat162float(x); }

// ---------------- RBF attention -> bf16, K padded to 224 with zeros ----------------
__global__ __launch_bounds__(64) void attn_kernel(
    const float* __restrict__ A_noise, const float* __restrict__ b_noise,
    const float* __restrict__ A_mean,  const float* __restrict__ b_mean,
    const float* __restrict__ A_std,   const float* __restrict__ b_std,
    const float* __restrict__ bwp, bf16* __restrict__ attn)
{
    int bi = blockIdx.x;            // b*196 + i
    int b = bi / NTOK, i = bi % NTOK;
    int lane = threadIdx.x;
    float A00 = A_mean[0] + softplus_f(A_std[0]) * A_noise[b * 4 + 0];
    float A01 = A_mean[1] + softplus_f(A_std[1]) * A_noise[b * 4 + 1];
    float A10 = A_mean[2] + softplus_f(A_std[2]) * A_noise[b * 4 + 2];
    float A11 = A_mean[3] + softplus_f(A_std[3]) * A_noise[b * 4 + 3];
    float bt0 = b_mean[0] + softplus_f(b_std[0]) * b_noise[b * 2 + 0];
    float bt1 = b_mean[1] + softplus_f(b_std[1]) * b_noise[b * 2 + 1];
    float inv_bw = 1.f / bwp[0];
    float Xi0 = (float)(i % 14), Xi1 = (float)(i / 14);
    float d[4];
    float mx = -1e30f;
    #pragma unroll
    for (int r = 0; r < 4; ++r) {
        int j = lane + r * 64;
        if (j < NTOK) {
            float Xj0 = (float)(j % 14), Xj1 = (float)(j / 14);
            float t0 = Xj0 * A00 + Xj1 * A10 + bt0 - Xi0;
            float t1 = Xj0 * A01 + Xj1 * A11 + bt1 - Xi1;
            d[r] = -(t0 * t0 + t1 * t1) * inv_bw;
            mx = fmaxf(mx, d[r]);
        } else d[r] = -1e30f;
    }
    for (int off = 1; off < 64; off <<= 1) mx = fmaxf(mx, __shfl_xor(mx, off));
    float e[4]; float s = 0.f;
    #pragma unroll
    for (int r = 0; r < 4; ++r) {
        int j = lane + r * 64;
        e[r] = (j < NTOK) ? expf(d[r] - mx) : 0.f;
        s += e[r];
    }
    for (int off = 1; off < 64; off <<= 1) s += __shfl_xor(s, off);
    float inv = 1.f / s;
    bf16* row = attn + (long)bi * KPAD;
    #pragma unroll
    for (int r = 0; r < 4; ++r) {
        int j = lane + r * 64;
        if (j < KPAD) row[j] = __float2bfloat16(j < NTOK ? e[r] * inv : 0.f);
    }
}

// ---------------- patchify ----------------
__global__ __launch_bounds__(256) void patchify_kernel(
    const float* __restrict__ img, bf16* __restrict__ Xp)
{
    long idx = (long)blockIdx.x * 256 + threadIdx.x;
    if (idx >= (long)ROWS * DIMC) return;
    int pd = (int)(idx % DIMC); long r = idx / DIMC;
    int n = (int)(r % NTOK); int b = (int)(r / NTOK);
    int c = pd % 3; int pp = pd / 3; int p2 = pp % 16; int p1 = pp / 16;
    int gw = n % 14, gh = n / 14;
    int h = gh * 16 + p1, w = gw * 16 + p2;
    Xp[idx] = __float2bfloat16(img[(((long)b * 3 + c) * 224 + h) * 224 + w]);
}

// ---------------- un-patchify ----------------
__global__ __launch_bounds__(256) void unpatchify_kernel(
    const float* __restrict__ xe, float* __restrict__ out)
{
    long idx = (long)blockIdx.x * 256 + threadIdx.x;
    if (idx >= (long)BATCH * 3 * 224 * 224) return;
    int w = (int)(idx % 224); long r = idx / 224;
    int h = (int)(r % 224); r /= 224;
    int c = (int)(r % 3); int b = (int)(r / 3);
    int gh = h / 16, p1 = h % 16, gw = w / 16, p2 = w % 16;
    int n = gh * 14 + gw;
    int pd = (p1 * 16 + p2) * 3 + c;
    out[idx] = xe[((long)b * NTOK + n) * DIMC + pd];
}

// ---------------- LayerNorm: fp32 in -> bf16 out ----------------
__global__ __launch_bounds__(256) void ln_kernel(
    const float* __restrict__ x, const float* __restrict__ g,
    const float* __restrict__ bb, bf16* __restrict__ y)
{
    int row = blockIdx.x;
    const float* xr = x + (long)row * DIMC;
    bf16* yr = y + (long)row * DIMC;
    int t = threadIdx.x;
    float v0 = xr[t], v1 = xr[t + 256], v2 = xr[t + 512];
    float s = v0 + v1 + v2;
    float s2 = v0 * v0 + v1 * v1 + v2 * v2;
    for (int off = 32; off; off >>= 1) { s += __shfl_down(s, off); s2 += __shfl_down(s2, off); }
    __shared__ float ps[4], ps2[4];
    if ((t & 63) == 0) { ps[t >> 6] = s; ps2[t >> 6] = s2; }
    __syncthreads();
    float S = ps[0] + ps[1] + ps[2] + ps[3];
    float S2 = ps2[0] + ps2[1] + ps2[2] + ps2[3];
    float mean = S * (1.f / DIMC);
    float var = S2 * (1.f / DIMC) - mean * mean;
    float rs = rsqrtf(var + 1e-5f);
    yr[t]       = __float2bfloat16((v0 - mean) * rs * g[t]       + bb[t]);
    yr[t + 256] = __float2bfloat16((v1 - mean) * rs * g[t + 256] + bb[t + 256]);
    yr[t + 512] = __float2bfloat16((v2 - mean) * rs * g[t + 512] + bb[t + 512]);
}

// ------- combine split-K partials + residual -> LN (MODE0) or bf16 cvt (MODE1) -------
template<int MODE>
__global__ __launch_bounds__(256) void combine_ln(
    const float* __restrict__ P0, const float* __restrict__ P1,
    const float* __restrict__ bias, const float* __restrict__ x,
    const float* __restrict__ g, const float* __restrict__ bb,
    bf16* __restrict__ zb)
{
    int row = blockIdx.x;
    const float* xr = x + (long)row * DIMC;
    const float* p0 = P0 + (long)row * DIMC;
    const float* p1 = P1 + (long)row * DIMC;
    bf16* zr = zb + (long)row * DIMC;
    int t = threadIdx.x;
    float v0 = xr[t]       + p0[t]       + p1[t]       + bias[t];
    float v1 = xr[t + 256] + p0[t + 256] + p1[t + 256] + bias[t + 256];
    float v2 = xr[t + 512] + p0[t + 512] + p1[t + 512] + bias[t + 512];
    if (MODE == 1) {
        zr[t]       = __float2bfloat16(v0);
        zr[t + 256] = __float2bfloat16(v1);
        zr[t + 512] = __float2bfloat16(v2);
        return;
    }
    float s = v0 + v1 + v2;
    float s2 = v0 * v0 + v1 * v1 + v2 * v2;
    for (int off = 32; off; off >>= 1) { s += __shfl_down(s, off); s2 += __shfl_down(s2, off); }
    __shared__ float ps[4], ps2[4];
    if ((t & 63) == 0) { ps[t >> 6] = s; ps2[t >> 6] = s2; }
    __syncthreads();
    float S = ps[0] + ps[1] + ps[2] + ps[3];
    float S2 = ps2[0] + ps2[1] + ps2[2] + ps2[3];
    float mean = S * (1.f / DIMC);
    float var = S2 * (1.f / DIMC) - mean * mean;
    float rs = rsqrtf(var + 1e-5f);
    zr[t]       = __float2bfloat16((v0 - mean) * rs * g[t]       + bb[t]);
    zr[t + 256] = __float2bfloat16((v1 - mean) * rs * g[t + 256] + bb[t + 256]);
    zr[t + 512] = __float2bfloat16((v2 - mean) * rs * g[t + 512] + bb[t + 512]);
}

// ---------------- transpose + convert ----------------
template<typename TIN>
__global__ __launch_bounds__(256) void transpose_cvt(
    const TIN* __restrict__ in, bf16* __restrict__ out,
    int R, int C, int ldin, int ldout, int Rpad, long sIn, long sOut)
{
    __shared__ float tile[32][33];
    in  += (long)blockIdx.z * sIn;
    out += (long)blockIdx.z * sOut;
    int c0 = blockIdx.x * 32, r0 = blockIdx.y * 32;
    int tx = threadIdx.x & 31, ty = threadIdx.x >> 5;
    #pragma unroll
    for (int i = 0; i < 32; i += 8) {
        int r = r0 + ty + i, c = c0 + tx;
        float v = 0.f;
        if (r < R && c < C) v = to_f(in[(long)r * ldin + c]);
        tile[ty + i][tx] = v;
    }
    __syncthreads();
    #pragma unroll
    for (int i = 0; i < 32; i += 8) {
        int c = c0 + ty + i, r = r0 + tx;
        if (c < C && r < Rpad) out[(long)c * ldout + r] = __float2bfloat16(tile[tx][ty + i]);
    }
}

// ---------------- strided cvt: Wv slice of Wqkv -> bf16 [6][768][768] ----------------
__global__ __launch_bounds__(256) void cvt_wv_kernel(const float* __restrict__ Wqkv,
                                                     bf16* __restrict__ out)
{
    long i = (long)blockIdx.x * 256 + threadIdx.x;
    if (i >= 6L * 768 * 768) return;
    int c = (int)(i % 768); long rl = i / 768;
    int r = (int)(rl % 768); int l = (int)(rl / 768);
    out[i] = __float2bfloat16(Wqkv[((long)l * 768 + r) * 2304 + 1536 + c]);
}

// ------- bf16 MFMA GEMM: 2-buffer counted-vmcnt + T2 source swizzle + T1 XCD swizzle -------
// f32 epilogue staged in TWO half-passes of [64][BN] (16KB): SMEM drops 32->24.5KB
// so OUTF32 BN=64 kernels fit 6 blocks/CU (was 5, LDS-capped). launch_bounds(256,4)
// keeps BN=128 at <=124 regs incl acc-AGPRs (4 blocks/CU).
template<int BN, int ACT, int ACCUM, int OUTF32, int GUARDM>
__global__ __launch_bounds__(256, 4) void gemm_bf16(
    const bf16* __restrict__ A, const bf16* __restrict__ Bt,
    const float* __restrict__ bias, void* __restrict__ Cv,
    int M, int K, int lda, int ldb, int ldc,
    long sA, long sB, long sC)
{
    constexpr int FN = BN / 32;
    constexpr int LPT = 2 + BN / 64;
    constexpr int ABUF = 128 * 32;            // elems per A buffer
    constexpr int BBUF = BN * 32;
    constexpr int SMEM_MAIN = 2 * (ABUF + BBUF) * 2;
    constexpr int SMEM_EPI  = OUTF32 ? (64 * BN * 4) : (128 * BN * 2);
    constexpr int SMEM = SMEM_MAIN > SMEM_EPI ? SMEM_MAIN : SMEM_EPI;
    __shared__ __align__(16) char smem[SMEM];
    bf16* As = (bf16*)smem;                   // [2][ABUF]
    bf16* Bs = (bf16*)(smem + 2 * ABUF * 2);  // [2][BBUF]
    A  += (long)blockIdx.z * sA;
    Bt += (long)blockIdx.z * sB;
    // ---- T1 bijective XCD swizzle over the x/y plane (m204) ----
    const int nwg = gridDim.x * gridDim.y;
    const int id = blockIdx.x + gridDim.x * blockIdx.y;
    const int q8 = nwg >> 3, r8 = nwg & 7;
    const int xcd = id & 7, jj = id >> 3;
    const int v = (xcd < r8 ? xcd * (q8 + 1) : r8 * (q8 + 1) + (xcd - r8) * q8) + jj;
    const int bx = v % gridDim.x, by = v / gridDim.x;
    const int m0 = by * 128, n0 = bx * BN;
    const int t = threadIdx.x, wave = t >> 6, lane = t & 63;
    const int lrow = t >> 2;
    const int lcol = ((t & 3) ^ ((lrow >> 1) & 3)) * 8;   // pre-swizzled source chunk
    const bf16* ag = A  + (long)(m0 + lrow) * lda + lcol;
    const bf16* bg = Bt + (long)(n0 + lrow) * ldb + lcol;
    const int fr = lane & 15, kq = lane >> 4;
    const int swz = (fr >> 1) & 3;                        // lane-constant read swizzle
    const int wr = wave >> 1, wc = wave & 1;
    f32x4 acc[4][FN];
    #pragma unroll
    for (int m = 0; m < 4; ++m)
        #pragma unroll
        for (int n = 0; n < FN; ++n) acc[m][n] = (f32x4){0.f, 0.f, 0.f, 0.f};

    auto stage = [&](int kt, int bufi) {
        const int k0 = kt << 5;
        bf16* ab = As + bufi * ABUF + wave * 512;
        bf16* bb = Bs + bufi * BBUF + wave * 512;
        gload16(ag + k0, ab);
        gload16(ag + 64 * (long)lda + k0, ab + 2048);
        gload16(bg + k0, bb);
        if constexpr (BN == 128) gload16(bg + 64 * (long)ldb + k0, bb + 2048);
    };
    auto compute = [&](int bufi) {
        const bf16* as = As + bufi * ABUF;
        const bf16* bs = Bs + bufi * BBUF;
        bf16x8 af[4], bfv[FN];
        #pragma unroll
        for (int m = 0; m < 4; ++m)
            af[m] = *(const bf16x8*)&as[(wr * 64 + m * 16 + fr) * 32 + ((kq ^ swz) << 3)];
        #pragma unroll
        for (int n = 0; n < FN; ++n)
            bfv[n] = *(const bf16x8*)&bs[(wc * (BN / 2) + n * 16 + fr) * 32 + ((kq ^ swz) << 3)];
        __builtin_amdgcn_s_setprio(1);
        #pragma unroll
        for (int m = 0; m < 4; ++m)
            #pragma unroll
            for (int n = 0; n < FN; ++n)
                acc[m][n] = __builtin_amdgcn_mfma_f32_16x16x32_bf16(af[m], bfv[n], acc[m][n], 0, 0, 0);
        __builtin_amdgcn_s_setprio(0);
    };

    const int nt = K >> 5;
    stage(0, 0);
    for (int it = 0; it < nt; ++it) {
        const int cb = it & 1;
        if (it) __builtin_amdgcn_s_barrier();            // B1: prev compute done
        if (it + 1 < nt) {
            stage(it + 1, cb ^ 1);
            asm volatile("s_waitcnt vmcnt(%0)" :: "n"(LPT) : "memory");
        } else {
            asm volatile("s_waitcnt vmcnt(0)" ::: "memory");
        }
        __builtin_amdgcn_s_barrier();                    // B2: tile-it fully in LDS
        __builtin_amdgcn_sched_barrier(0);
        compute(cb);
    }
    __syncthreads();                                     // protect epilogue LDS reuse

    const int rbase = kq * 4;
    if constexpr (OUTF32) {
        static_assert(BN == 64, "f32 epilogue assumes BN=64");
        float* Cs = (float*)smem;                        // [64][BN] = 16KB (half-tile)
        float* Cp = (float*)Cv + (long)blockIdx.z * sC;
        #pragma unroll
        for (int h = 0; h < 2; ++h) {
            if (h) __syncthreads();
            if (wr == h) {                               // waves owning rows h*64..h*64+63
                #pragma unroll
                for (int n = 0; n < FN; ++n) {
                    int lc = wc * (BN / 2) + n * 16 + fr;
                    float bi = bias ? bias[n0 + lc] : 0.f;
                    #pragma unroll
                    for (int m = 0; m < 4; ++m)
                        #pragma unroll
                        for (int r = 0; r < 4; ++r) {
                            int lr = m * 16 + rbase + r; // local 0..63
                            float vv = acc[m][n][r] + bi;
                            if (ACT) vv = gelu_f(vv);
                            Cs[lr * BN + lc] = vv;
                        }
                }
            }
            __syncthreads();
            #pragma unroll
            for (int i = 0; i < (64 * BN) / (256 * 4); ++i) {
                int chunk = i * 256 + t;
                int row = chunk / (BN / 4), c4 = (chunk % (BN / 4)) * 4;
                int gm = m0 + h * 64 + row;
                if (GUARDM && gm >= M) continue;
                float4 v4 = *(const float4*)&Cs[row * BN + c4];
                float* p = Cp + (long)gm * ldc + n0 + c4;
                if (ACCUM) {
                    float4 o4 = *(const float4*)p;
                    v4.x += o4.x; v4.y += o4.y; v4.z += o4.z; v4.w += o4.w;
                }
                *(float4*)p = v4;
            }
        }
    } else {
        bf16* Cs = (bf16*)smem;
        #pragma unroll
        for (int n = 0; n < FN; ++n) {
            int lc = wc * (BN / 2) + n * 16 + fr;
            float bi = bias ? bias[n0 + lc] : 0.f;
            #pragma unroll
            for (int m = 0; m < 4; ++m)
                #pragma unroll
                for (int r = 0; r < 4; ++r) {
                    int lr = wr * 64 + m * 16 + rbase + r;
                    float vv = acc[m][n][r] + bi;
                    if (ACT) vv = gelu_f(vv);
                    Cs[lr * BN + lc] = __float2bfloat16(vv);
                }
        }
        __syncthreads();
        bf16* Cp = (bf16*)Cv + (long)blockIdx.z * sC;
        #pragma unroll
        for (int i = 0; i < (128 * BN) / (256 * 8); ++i) {
            int chunk = i * 256 + t;
            int row = chunk / (BN / 8), c8 = (chunk % (BN / 8)) * 8;
            int gm = m0 + row;
            if (GUARDM && gm >= M) continue;
            *(bf16x8*)(Cp + (long)gm * ldc + n0 + c8) = *(const bf16x8*)&Cs[row * BN + c8];
        }
    }
}

extern "C" void kernel_launch(void* const* d_in, const int* in_sizes, int n_in,
                              void* d_out, int out_size, void* d_ws, size_t ws_size,
                              hipStream_t stream) {
    const float* img     = (const float*)d_in[0];
    const float* A_noise = (const float*)d_in[2];
    const float* b_noise = (const float*)d_in[3];
    const float* A_mean  = (const float*)d_in[4];
    const float* b_mean  = (const float*)d_in[5];
    const float* A_std   = (const float*)d_in[6];
    const float* b_std   = (const float*)d_in[7];
    const float* band_w  = (const float*)d_in[8];
    const float* Wp      = (const float*)d_in[9];
    const float* bp      = (const float*)d_in[10];
    const float* ln1_g   = (const float*)d_in[11];
    const float* ln1_b   = (const float*)d_in[12];
    const float* Wqkv    = (const float*)d_in[13];
    const float* Wout    = (const float*)d_in[14];
    const float* bout    = (const float*)d_in[15];
    const float* ln2_g   = (const float*)d_in[16];
    const float* ln2_b   = (const float*)d_in[17];
    const float* Wff1    = (const float*)d_in[18];
    const float* bff1    = (const float*)d_in[19];
    const float* Wff2    = (const float*)d_in[20];
    const float* bff2    = (const float*)d_in[21];
    const float* Wep     = (const float*)d_in[22];
    const float* bep     = (const float*)d_in[23];
    float* out = (float*)d_out;

    // ---- workspace carve-up ----
    char* w = (char*)d_ws;
    bf16* WpT  = (bf16*)w; w += 768L * 768 * 2;
    bf16* WepT = (bf16*)w; w += 768L * 768 * 2;
    bf16* WvoT = (bf16*)w; w += 6L * 768 * 768 * 2;      // (Wv@Wout)^T per layer
    bf16* Wf1T = (bf16*)w; w += 6L * 3072 * 768 * 2;
    bf16* Wf2T = (bf16*)w; w += 6L * 768 * 3072 * 2;
    bf16* attnb = (bf16*)w; w += (long)(ROWS + 64) * KPAD * 2;
    bf16* Xpb  = (bf16*)w; w += (long)ROWS * DIMC * 2;   // ┐ P0/P1 overlay during FF2
    bf16* yb   = (bf16*)w; w += (long)ROWS * DIMC * 2;   // │ (all 4 dead by then)
    bf16* yTb  = (bf16*)w; w += (long)BATCH * DIMC * KPAD * 2; // │
    bf16* ya   = (bf16*)w; w += (long)ROWS * DIMC * 2;   // ┘
    bf16* h1b  = (bf16*)w; w += (long)ROWS * MLPD * 2;   // prep aliases + zb/xe
    float* x   = (float*)w; w += (long)ROWS * DIMC * 4;
    // overlays
    float* P0 = (float*)Xpb;                 // 6272*768 f32
    float* P1 = P0 + (long)ROWS * DIMC;      // spans into yb/yTb (dead during FF2)
    bf16* WoT = h1b;                         // prep only
    bf16* Wvb = h1b + 6L * 768 * 768;        // prep only
    bf16* zb  = h1b;                         // LN1-out / final bf16 x
    float* xe = (float*)((char*)h1b + (long)ROWS * DIMC * 2);  // final f32 out

    // ---- prep ----
    transpose_cvt<float><<<dim3(24, 24, 1), 256, 0, stream>>>(Wp,  WpT,  768, 768, 768, 768, 768, 0, 0);
    transpose_cvt<float><<<dim3(24, 24, 1), 256, 0, stream>>>(Wep, WepT, 768, 768, 768, 768, 768, 0, 0);
    transpose_cvt<float><<<dim3(24, 24, 6), 256, 0, stream>>>(Wout, WoT, 768, 768, 768, 768, 768,
                                                              768L * 768, 768L * 768);
    cvt_wv_kernel<<<(int)((6L * 768 * 768 + 255) / 256), 256, 0, stream>>>(Wqkv, Wvb);
    transpose_cvt<float><<<dim3(96, 24, 6), 256, 0, stream>>>(Wff1, Wf1T, 768, 3072, 3072, 768, 768,
                                                              768L * 3072, 3072L * 768);
    transpose_cvt<float><<<dim3(24, 96, 6), 256, 0, stream>>>(Wff2, Wf2T, 3072, 768, 768, 3072, 3072,
                                                              3072L * 768, 768L * 3072);
    gemm_bf16<64, 0, 0, 0, 0><<<dim3(12, 6, 6), 256, 0, stream>>>(
        WoT, Wvb, nullptr, WvoT, 768, 768, 768, 768, 768,
        768L * 768, 768L * 768, 768L * 768);

    // ---- attention matrix ----
    attn_kernel<<<ROWS, 64, 0, stream>>>(A_noise, b_noise, A_mean, b_mean, A_std, b_std, band_w, attnb);

    // ---- patchify + embed + LN1(0) ----
    patchify_kernel<<<(ROWS * DIMC + 255) / 256, 256, 0, stream>>>(img, Xpb);
    gemm_bf16<64, 0, 0, 1, 0><<<dim3(12, 49, 1), 256, 0, stream>>>(
        Xpb, WpT, bp, x, ROWS, 768, 768, 768, 768, 0, 0, 0);
    ln_kernel<<<ROWS, 256, 0, stream>>>(x, ln1_g, ln1_b, zb);

    for (int l = 0; l < 6; ++l) {
        // yT[b][768][224] from zb
        transpose_cvt<bf16><<<dim3(24, 7, 32), 256, 0, stream>>>(
            zb, yTb, NTOK, 768, 768, KPAD, KPAD, (long)NTOK * 768, (long)768 * KPAD);
        // ya[b] = attn[b] @ y[b]
        gemm_bf16<64, 0, 0, 0, 1><<<dim3(12, 2, BATCH), 256, 0, stream>>>(
            attnb, yTb, nullptr, ya, NTOK, KPAD, KPAD, KPAD, 768,
            (long)NTOK * KPAD, (long)768 * KPAD, (long)NTOK * 768);
        // x = ya @ Wvo + bout (f32, no residual)
        gemm_bf16<64, 0, 0, 1, 0><<<dim3(12, 49, 1), 256, 0, stream>>>(
            ya, WvoT + (long)l * 768 * 768, bout + l * 768, x, ROWS, 768, 768, 768, 768, 0, 0, 0);
        // LN2
        ln_kernel<<<ROWS, 256, 0, stream>>>(x, ln2_g + l * 768, ln2_b + l * 768, yb);
        // h1 = gelu(y @ Wff1 + bff1)   [BN=128 2-buffer, launch_bounds(256,4)]
        gemm_bf16<128, 1, 0, 0, 0><<<dim3(24, 49, 1), 256, 0, stream>>>(
            yb, Wf1T + (long)l * 3072 * 768, bff1 + l * 3072, h1b, ROWS, 768, 768, 768, 3072, 0, 0, 0);
        // FF2 split-K=2 -> f32 partials P0,P1
        gemm_bf16<64, 0, 0, 1, 0><<<dim3(12, 49, 2), 256, 0, stream>>>(
            h1b, Wf2T + (long)l * 768 * 3072, nullptr, P0,
            ROWS, 1536, 3072, 3072, 768, 1536, 1536, (long)ROWS * DIMC);
        // zb = LN1_{l+1}(x + P0 + P1 + bff2)
        if (l < 5)
            combine_ln<0><<<ROWS, 256, 0, stream>>>(P0, P1, bff2 + l * 768, x,
                ln1_g + (l + 1) * 768, ln1_b + (l + 1) * 768, zb);
        else
            combine_ln<1><<<ROWS, 256, 0, stream>>>(P0, P1, bff2 + l * 768, x,
                ln1_g, ln1_b, zb);
    }

    // ---- final projection + un-patchify ----
    gemm_bf16<64, 0, 0, 1, 0><<<dim3(12, 49, 1), 256, 0, stream>>>(
        zb, WepT, bep, xe, ROWS, 768, 768, 768, 768, 0, 0, 0);
    unpatchify_kernel<<<(BATCH * 3 * 224 * 224 + 255) / 256, 256, 0, stream>>>(xe, out);
}

// Round 16
// 1123.739 us; speedup vs baseline: 1.0105x; 1.0105x over previous
//
#include <hip/hip_runtime.h>
#include <hip/hip_bf16.h>
#include <math.h>

#define NTOK 196
#define KPAD 224
#define BATCH 32
#define ROWS (BATCH * NTOK)   // 6272
#define DIMC 768
#define MLPD 3072

typedef __hip_bfloat16 bf16;
typedef short bf16x8 __attribute__((ext_vector_type(8)));
typedef float f32x4 __attribute__((ext_vector_type(4)));

__device__ __forceinline__ void gload16(const void* g, void* l) {
    __builtin_amdgcn_global_load_lds(
        (__attribute__((address_space(1))) void*)const_cast<void*>(g),
        (__attribute__((address_space(3))) void*)l, 16, 0, 0);
}

__device__ __forceinline__ float softplus_f(float x) {
    return fmaxf(x, 0.f) + log1pf(expf(-fabsf(x)));
}
__device__ __forceinline__ float gelu_f(float x) {
    return 0.5f * x * (1.f + erff(x * 0.70710678118654752f));
}
__device__ __forceinline__ float to_f(float x) { return x; }
__device__ __forceinline__ float to_f(bf16 x) { return __bfloat162float(x); }

// ---------------- RBF attention -> bf16, K padded to 224 with zeros ----------------
__global__ __launch_bounds__(64) void attn_kernel(
    const float* __restrict__ A_noise, const float* __restrict__ b_noise,
    const float* __restrict__ A_mean,  const float* __restrict__ b_mean,
    const float* __restrict__ A_std,   const float* __restrict__ b_std,
    const float* __restrict__ bwp, bf16* __restrict__ attn)
{
    int bi = blockIdx.x;            // b*196 + i
    int b = bi / NTOK, i = bi % NTOK;
    int lane = threadIdx.x;
    float A00 = A_mean[0] + softplus_f(A_std[0]) * A_noise[b * 4 + 0];
    float A01 = A_mean[1] + softplus_f(A_std[1]) * A_noise[b * 4 + 1];
    float A10 = A_mean[2] + softplus_f(A_std[2]) * A_noise[b * 4 + 2];
    float A11 = A_mean[3] + softplus_f(A_std[3]) * A_noise[b * 4 + 3];
    float bt0 = b_mean[0] + softplus_f(b_std[0]) * b_noise[b * 2 + 0];
    float bt1 = b_mean[1] + softplus_f(b_std[1]) * b_noise[b * 2 + 1];
    float inv_bw = 1.f / bwp[0];
    float Xi0 = (float)(i % 14), Xi1 = (float)(i / 14);
    float d[4];
    float mx = -1e30f;
    #pragma unroll
    for (int r = 0; r < 4; ++r) {
        int j = lane + r * 64;
        if (j < NTOK) {
            float Xj0 = (float)(j % 14), Xj1 = (float)(j / 14);
            float t0 = Xj0 * A00 + Xj1 * A10 + bt0 - Xi0;
            float t1 = Xj0 * A01 + Xj1 * A11 + bt1 - Xi1;
            d[r] = -(t0 * t0 + t1 * t1) * inv_bw;
            mx = fmaxf(mx, d[r]);
        } else d[r] = -1e30f;
    }
    for (int off = 1; off < 64; off <<= 1) mx = fmaxf(mx, __shfl_xor(mx, off));
    float e[4]; float s = 0.f;
    #pragma unroll
    for (int r = 0; r < 4; ++r) {
        int j = lane + r * 64;
        e[r] = (j < NTOK) ? expf(d[r] - mx) : 0.f;
        s += e[r];
    }
    for (int off = 1; off < 64; off <<= 1) s += __shfl_xor(s, off);
    float inv = 1.f / s;
    bf16* row = attn + (long)bi * KPAD;
    #pragma unroll
    for (int r = 0; r < 4; ++r) {
        int j = lane + r * 64;
        if (j < KPAD) row[j] = __float2bfloat16(j < NTOK ? e[r] * inv : 0.f);
    }
}

// ---------------- patchify ----------------
__global__ __launch_bounds__(256) void patchify_kernel(
    const float* __restrict__ img, bf16* __restrict__ Xp)
{
    long idx = (long)blockIdx.x * 256 + threadIdx.x;
    if (idx >= (long)ROWS * DIMC) return;
    int pd = (int)(idx % DIMC); long r = idx / DIMC;
    int n = (int)(r % NTOK); int b = (int)(r / NTOK);
    int c = pd % 3; int pp = pd / 3; int p2 = pp % 16; int p1 = pp / 16;
    int gw = n % 14, gh = n / 14;
    int h = gh * 16 + p1, w = gw * 16 + p2;
    Xp[idx] = __float2bfloat16(img[(((long)b * 3 + c) * 224 + h) * 224 + w]);
}

// ---------------- un-patchify ----------------
__global__ __launch_bounds__(256) void unpatchify_kernel(
    const float* __restrict__ xe, float* __restrict__ out)
{
    long idx = (long)blockIdx.x * 256 + threadIdx.x;
    if (idx >= (long)BATCH * 3 * 224 * 224) return;
    int w = (int)(idx % 224); long r = idx / 224;
    int h = (int)(r % 224); r /= 224;
    int c = (int)(r % 3); int b = (int)(r / 3);
    int gh = h / 16, p1 = h % 16, gw = w / 16, p2 = w % 16;
    int n = gh * 14 + gw;
    int pd = (p1 * 16 + p2) * 3 + c;
    out[idx] = xe[((long)b * NTOK + n) * DIMC + pd];
}

// ---------------- LayerNorm: fp32 in -> bf16 out ----------------
__global__ __launch_bounds__(256) void ln_kernel(
    const float* __restrict__ x, const float* __restrict__ g,
    const float* __restrict__ bb, bf16* __restrict__ y)
{
    int row = blockIdx.x;
    const float* xr = x + (long)row * DIMC;
    bf16* yr = y + (long)row * DIMC;
    int t = threadIdx.x;
    float v0 = xr[t], v1 = xr[t + 256], v2 = xr[t + 512];
    float s = v0 + v1 + v2;
    float s2 = v0 * v0 + v1 * v1 + v2 * v2;
    for (int off = 32; off; off >>= 1) { s += __shfl_down(s, off); s2 += __shfl_down(s2, off); }
    __shared__ float ps[4], ps2[4];
    if ((t & 63) == 0) { ps[t >> 6] = s; ps2[t >> 6] = s2; }
    __syncthreads();
    float S = ps[0] + ps[1] + ps[2] + ps[3];
    float S2 = ps2[0] + ps2[1] + ps2[2] + ps2[3];
    float mean = S * (1.f / DIMC);
    float var = S2 * (1.f / DIMC) - mean * mean;
    float rs = rsqrtf(var + 1e-5f);
    yr[t]       = __float2bfloat16((v0 - mean) * rs * g[t]       + bb[t]);
    yr[t + 256] = __float2bfloat16((v1 - mean) * rs * g[t + 256] + bb[t + 256]);
    yr[t + 512] = __float2bfloat16((v2 - mean) * rs * g[t + 512] + bb[t + 512]);
}

// ------- combine split-K partials + residual -> LN (MODE0) or bf16 cvt (MODE1) -------
template<int MODE>
__global__ __launch_bounds__(256) void combine_ln(
    const float* __restrict__ P0, const float* __restrict__ P1,
    const float* __restrict__ bias, const float* __restrict__ x,
    const float* __restrict__ g, const float* __restrict__ bb,
    bf16* __restrict__ zb)
{
    int row = blockIdx.x;
    const float* xr = x + (long)row * DIMC;
    const float* p0 = P0 + (long)row * DIMC;
    const float* p1 = P1 + (long)row * DIMC;
    bf16* zr = zb + (long)row * DIMC;
    int t = threadIdx.x;
    float v0 = xr[t]       + p0[t]       + p1[t]       + bias[t];
    float v1 = xr[t + 256] + p0[t + 256] + p1[t + 256] + bias[t + 256];
    float v2 = xr[t + 512] + p0[t + 512] + p1[t + 512] + bias[t + 512];
    if (MODE == 1) {
        zr[t]       = __float2bfloat16(v0);
        zr[t + 256] = __float2bfloat16(v1);
        zr[t + 512] = __float2bfloat16(v2);
        return;
    }
    float s = v0 + v1 + v2;
    float s2 = v0 * v0 + v1 * v1 + v2 * v2;
    for (int off = 32; off; off >>= 1) { s += __shfl_down(s, off); s2 += __shfl_down(s2, off); }
    __shared__ float ps[4], ps2[4];
    if ((t & 63) == 0) { ps[t >> 6] = s; ps2[t >> 6] = s2; }
    __syncthreads();
    float S = ps[0] + ps[1] + ps[2] + ps[3];
    float S2 = ps2[0] + ps2[1] + ps2[2] + ps2[3];
    float mean = S * (1.f / DIMC);
    float var = S2 * (1.f / DIMC) - mean * mean;
    float rs = rsqrtf(var + 1e-5f);
    zr[t]       = __float2bfloat16((v0 - mean) * rs * g[t]       + bb[t]);
    zr[t + 256] = __float2bfloat16((v1 - mean) * rs * g[t + 256] + bb[t + 256]);
    zr[t + 512] = __float2bfloat16((v2 - mean) * rs * g[t + 512] + bb[t + 512]);
}

// ---------------- transpose + convert ----------------
template<typename TIN>
__global__ __launch_bounds__(256) void transpose_cvt(
    const TIN* __restrict__ in, bf16* __restrict__ out,
    int R, int C, int ldin, int ldout, int Rpad, long sIn, long sOut)
{
    __shared__ float tile[32][33];
    in  += (long)blockIdx.z * sIn;
    out += (long)blockIdx.z * sOut;
    int c0 = blockIdx.x * 32, r0 = blockIdx.y * 32;
    int tx = threadIdx.x & 31, ty = threadIdx.x >> 5;
    #pragma unroll
    for (int i = 0; i < 32; i += 8) {
        int r = r0 + ty + i, c = c0 + tx;
        float v = 0.f;
        if (r < R && c < C) v = to_f(in[(long)r * ldin + c]);
        tile[ty + i][tx] = v;
    }
    __syncthreads();
    #pragma unroll
    for (int i = 0; i < 32; i += 8) {
        int c = c0 + ty + i, r = r0 + tx;
        if (c < C && r < Rpad) out[(long)c * ldout + r] = __float2bfloat16(tile[tx][ty + i]);
    }
}

// ---------------- strided cvt: Wv slice of Wqkv -> bf16 [6][768][768] ----------------
__global__ __launch_bounds__(256) void cvt_wv_kernel(const float* __restrict__ Wqkv,
                                                     bf16* __restrict__ out)
{
    long i = (long)blockIdx.x * 256 + threadIdx.x;
    if (i >= 6L * 768 * 768) return;
    int c = (int)(i % 768); long rl = i / 768;
    int r = (int)(rl % 768); int l = (int)(rl / 768);
    out[i] = __float2bfloat16(Wqkv[((long)l * 768 + r) * 2304 + 1536 + c]);
}

// ------- bf16 MFMA GEMM: 2-buffer counted-vmcnt + T2 source swizzle + T1 XCD swizzle -------
// __launch_bounds__(256,4): cap regalloc at 4 waves/EU (<=128 regs incl acc-AGPRs)
// so BN=128 fits 4 blocks/CU. BN=64 (72 regs) unaffected.
template<int BN, int ACT, int ACCUM, int OUTF32, int GUARDM>
__global__ __launch_bounds__(256, 4) void gemm_bf16(
    const bf16* __restrict__ A, const bf16* __restrict__ Bt,
    const float* __restrict__ bias, void* __restrict__ Cv,
    int M, int K, int lda, int ldb, int ldc,
    long sA, long sB, long sC)
{
    constexpr int FN = BN / 32;
    constexpr int LPT = 2 + BN / 64;
    constexpr int ABUF = 128 * 32;            // elems per A buffer
    constexpr int BBUF = BN * 32;
    constexpr int SMEM_MAIN = 2 * (ABUF + BBUF) * 2;
    constexpr int SMEM_EPI  = OUTF32 ? (128 * BN * 4) : (128 * BN * 2);
    constexpr int SMEM = SMEM_MAIN > SMEM_EPI ? SMEM_MAIN : SMEM_EPI;
    __shared__ __align__(16) char smem[SMEM];
    bf16* As = (bf16*)smem;                   // [2][ABUF]
    bf16* Bs = (bf16*)(smem + 2 * ABUF * 2);  // [2][BBUF]
    A  += (long)blockIdx.z * sA;
    Bt += (long)blockIdx.z * sB;
    // ---- T1 bijective XCD swizzle over the x/y plane (m204) ----
    const int nwg = gridDim.x * gridDim.y;
    const int id = blockIdx.x + gridDim.x * blockIdx.y;
    const int q8 = nwg >> 3, r8 = nwg & 7;
    const int xcd = id & 7, jj = id >> 3;
    const int v = (xcd < r8 ? xcd * (q8 + 1) : r8 * (q8 + 1) + (xcd - r8) * q8) + jj;
    const int bx = v % gridDim.x, by = v / gridDim.x;
    const int m0 = by * 128, n0 = bx * BN;
    const int t = threadIdx.x, wave = t >> 6, lane = t & 63;
    const int lrow = t >> 2;
    const int lcol = ((t & 3) ^ ((lrow >> 1) & 3)) * 8;   // pre-swizzled source chunk
    const bf16* ag = A  + (long)(m0 + lrow) * lda + lcol;
    const bf16* bg = Bt + (long)(n0 + lrow) * ldb + lcol;
    const int fr = lane & 15, kq = lane >> 4;
    const int swz = (fr >> 1) & 3;                        // lane-constant read swizzle
    const int wr = wave >> 1, wc = wave & 1;
    f32x4 acc[4][FN];
    #pragma unroll
    for (int m = 0; m < 4; ++m)
        #pragma unroll
        for (int n = 0; n < FN; ++n) acc[m][n] = (f32x4){0.f, 0.f, 0.f, 0.f};

    auto stage = [&](int kt, int bufi) {
        const int k0 = kt << 5;
        bf16* ab = As + bufi * ABUF + wave * 512;
        bf16* bb = Bs + bufi * BBUF + wave * 512;
        gload16(ag + k0, ab);
        gload16(ag + 64 * (long)lda + k0, ab + 2048);
        gload16(bg + k0, bb);
        if constexpr (BN == 128) gload16(bg + 64 * (long)ldb + k0, bb + 2048);
    };
    auto compute = [&](int bufi) {
        const bf16* as = As + bufi * ABUF;
        const bf16* bs = Bs + bufi * BBUF;
        bf16x8 af[4], bfv[FN];
        #pragma unroll
        for (int m = 0; m < 4; ++m)
            af[m] = *(const bf16x8*)&as[(wr * 64 + m * 16 + fr) * 32 + ((kq ^ swz) << 3)];
        #pragma unroll
        for (int n = 0; n < FN; ++n)
            bfv[n] = *(const bf16x8*)&bs[(wc * (BN / 2) + n * 16 + fr) * 32 + ((kq ^ swz) << 3)];
        __builtin_amdgcn_s_setprio(1);
        #pragma unroll
        for (int m = 0; m < 4; ++m)
            #pragma unroll
            for (int n = 0; n < FN; ++n)
                acc[m][n] = __builtin_amdgcn_mfma_f32_16x16x32_bf16(af[m], bfv[n], acc[m][n], 0, 0, 0);
        __builtin_amdgcn_s_setprio(0);
    };

    const int nt = K >> 5;
    stage(0, 0);
    for (int it = 0; it < nt; ++it) {
        const int cb = it & 1;
        if (it) __builtin_amdgcn_s_barrier();            // B1: prev compute done
        if (it + 1 < nt) {
            stage(it + 1, cb ^ 1);
            asm volatile("s_waitcnt vmcnt(%0)" :: "n"(LPT) : "memory");
        } else {
            asm volatile("s_waitcnt vmcnt(0)" ::: "memory");
        }
        __builtin_amdgcn_s_barrier();                    // B2: tile-it fully in LDS
        __builtin_amdgcn_sched_barrier(0);
        compute(cb);
    }
    __syncthreads();                                     // protect epilogue LDS reuse

    const int rbase = kq * 4;
    if constexpr (OUTF32) {
        static_assert(BN == 64, "f32 epilogue assumes BN=64");
        float* Cs = (float*)smem;
        #pragma unroll
        for (int n = 0; n < FN; ++n) {
            int lc = wc * (BN / 2) + n * 16 + fr;
            float bi = bias ? bias[n0 + lc] : 0.f;
            #pragma unroll
            for (int m = 0; m < 4; ++m)
                #pragma unroll
                for (int r = 0; r < 4; ++r) {
                    int lr = wr * 64 + m * 16 + rbase + r;
                    float vv = acc[m][n][r] + bi;
                    if (ACT) vv = gelu_f(vv);
                    Cs[lr * BN + lc] = vv;
                }
        }
        __syncthreads();
        float* Cp = (float*)Cv + (long)blockIdx.z * sC;
        #pragma unroll
        for (int i = 0; i < (128 * BN) / (256 * 4); ++i) {
            int chunk = i * 256 + t;
            int row = chunk / (BN / 4), c4 = (chunk % (BN / 4)) * 4;
            int gm = m0 + row;
            if (GUARDM && gm >= M) continue;
            float4 v4 = *(const float4*)&Cs[row * BN + c4];
            float* p = Cp + (long)gm * ldc + n0 + c4;
            if (ACCUM) {
                float4 o4 = *(const float4*)p;
                v4.x += o4.x; v4.y += o4.y; v4.z += o4.z; v4.w += o4.w;
            }
            *(float4*)p = v4;
        }
    } else {
        bf16* Cs = (bf16*)smem;
        #pragma unroll
        for (int n = 0; n < FN; ++n) {
            int lc = wc * (BN / 2) + n * 16 + fr;
            float bi = bias ? bias[n0 + lc] : 0.f;
            #pragma unroll
            for (int m = 0; m < 4; ++m)
                #pragma unroll
                for (int r = 0; r < 4; ++r) {
                    int lr = wr * 64 + m * 16 + rbase + r;
                    float vv = acc[m][n][r] + bi;
                    if (ACT) vv = gelu_f(vv);
                    Cs[lr * BN + lc] = __float2bfloat16(vv);
                }
        }
        __syncthreads();
        bf16* Cp = (bf16*)Cv + (long)blockIdx.z * sC;
        #pragma unroll
        for (int i = 0; i < (128 * BN) / (256 * 8); ++i) {
            int chunk = i * 256 + t;
            int row = chunk / (BN / 8), c8 = (chunk % (BN / 8)) * 8;
            int gm = m0 + row;
            if (GUARDM && gm >= M) continue;
            *(bf16x8*)(Cp + (long)gm * ldc + n0 + c8) = *(const bf16x8*)&Cs[row * BN + c8];
        }
    }
}

extern "C" void kernel_launch(void* const* d_in, const int* in_sizes, int n_in,
                              void* d_out, int out_size, void* d_ws, size_t ws_size,
                              hipStream_t stream) {
    const float* img     = (const float*)d_in[0];
    const float* A_noise = (const float*)d_in[2];
    const float* b_noise = (const float*)d_in[3];
    const float* A_mean  = (const float*)d_in[4];
    const float* b_mean  = (const float*)d_in[5];
    const float* A_std   = (const float*)d_in[6];
    const float* b_std   = (const float*)d_in[7];
    const float* band_w  = (const float*)d_in[8];
    const float* Wp      = (const float*)d_in[9];
    const float* bp      = (const float*)d_in[10];
    const float* ln1_g   = (const float*)d_in[11];
    const float* ln1_b   = (const float*)d_in[12];
    const float* Wqkv    = (const float*)d_in[13];
    const float* Wout    = (const float*)d_in[14];
    const float* bout    = (const float*)d_in[15];
    const float* ln2_g   = (const float*)d_in[16];
    const float* ln2_b   = (const float*)d_in[17];
    const float* Wff1    = (const float*)d_in[18];
    const float* bff1    = (const float*)d_in[19];
    const float* Wff2    = (const float*)d_in[20];
    const float* bff2    = (const float*)d_in[21];
    const float* Wep     = (const float*)d_in[22];
    const float* bep     = (const float*)d_in[23];
    float* out = (float*)d_out;

    // ---- workspace carve-up ----
    char* w = (char*)d_ws;
    bf16* WpT  = (bf16*)w; w += 768L * 768 * 2;
    bf16* WepT = (bf16*)w; w += 768L * 768 * 2;
    bf16* WvoT = (bf16*)w; w += 6L * 768 * 768 * 2;      // (Wv@Wout)^T per layer
    bf16* Wf1T = (bf16*)w; w += 6L * 3072 * 768 * 2;
    bf16* Wf2T = (bf16*)w; w += 6L * 768 * 3072 * 2;
    bf16* attnb = (bf16*)w; w += (long)(ROWS + 64) * KPAD * 2;
    bf16* Xpb  = (bf16*)w; w += (long)ROWS * DIMC * 2;   // ┐ P0/P1 overlay during FF2
    bf16* yb   = (bf16*)w; w += (long)ROWS * DIMC * 2;   // │ (all 4 dead by then)
    bf16* yTb  = (bf16*)w; w += (long)BATCH * DIMC * KPAD * 2; // │
    bf16* ya   = (bf16*)w; w += (long)ROWS * DIMC * 2;   // ┘
    bf16* h1b  = (bf16*)w; w += (long)ROWS * MLPD * 2;   // prep aliases + zb/xe
    float* x   = (float*)w; w += (long)ROWS * DIMC * 4;
    // overlays
    float* P0 = (float*)Xpb;                 // 6272*768 f32
    float* P1 = P0 + (long)ROWS * DIMC;      // spans into yb/yTb (dead during FF2)
    bf16* WoT = h1b;                         // prep only
    bf16* Wvb = h1b + 6L * 768 * 768;        // prep only
    bf16* zb  = h1b;                         // LN1-out / final bf16 x
    float* xe = (float*)((char*)h1b + (long)ROWS * DIMC * 2);  // final f32 out

    // ---- prep ----
    transpose_cvt<float><<<dim3(24, 24, 1), 256, 0, stream>>>(Wp,  WpT,  768, 768, 768, 768, 768, 0, 0);
    transpose_cvt<float><<<dim3(24, 24, 1), 256, 0, stream>>>(Wep, WepT, 768, 768, 768, 768, 768, 0, 0);
    transpose_cvt<float><<<dim3(24, 24, 6), 256, 0, stream>>>(Wout, WoT, 768, 768, 768, 768, 768,
                                                              768L * 768, 768L * 768);
    cvt_wv_kernel<<<(int)((6L * 768 * 768 + 255) / 256), 256, 0, stream>>>(Wqkv, Wvb);
    transpose_cvt<float><<<dim3(96, 24, 6), 256, 0, stream>>>(Wff1, Wf1T, 768, 3072, 3072, 768, 768,
                                                              768L * 3072, 3072L * 768);
    transpose_cvt<float><<<dim3(24, 96, 6), 256, 0, stream>>>(Wff2, Wf2T, 3072, 768, 768, 3072, 3072,
                                                              3072L * 768, 768L * 3072);
    gemm_bf16<64, 0, 0, 0, 0><<<dim3(12, 6, 6), 256, 0, stream>>>(
        WoT, Wvb, nullptr, WvoT, 768, 768, 768, 768, 768,
        768L * 768, 768L * 768, 768L * 768);

    // ---- attention matrix ----
    attn_kernel<<<ROWS, 64, 0, stream>>>(A_noise, b_noise, A_mean, b_mean, A_std, b_std, band_w, attnb);

    // ---- patchify + embed + LN1(0) ----
    patchify_kernel<<<(ROWS * DIMC + 255) / 256, 256, 0, stream>>>(img, Xpb);
    gemm_bf16<64, 0, 0, 1, 0><<<dim3(12, 49, 1), 256, 0, stream>>>(
        Xpb, WpT, bp, x, ROWS, 768, 768, 768, 768, 0, 0, 0);
    ln_kernel<<<ROWS, 256, 0, stream>>>(x, ln1_g, ln1_b, zb);

    for (int l = 0; l < 6; ++l) {
        // yT[b][768][224] from zb
        transpose_cvt<bf16><<<dim3(24, 7, 32), 256, 0, stream>>>(
            zb, yTb, NTOK, 768, 768, KPAD, KPAD, (long)NTOK * 768, (long)768 * KPAD);
        // ya[b] = attn[b] @ y[b]
        gemm_bf16<64, 0, 0, 0, 1><<<dim3(12, 2, BATCH), 256, 0, stream>>>(
            attnb, yTb, nullptr, ya, NTOK, KPAD, KPAD, KPAD, 768,
            (long)NTOK * KPAD, (long)768 * KPAD, (long)NTOK * 768);
        // x = ya @ Wvo + bout (f32, no residual)
        gemm_bf16<64, 0, 0, 1, 0><<<dim3(12, 49, 1), 256, 0, stream>>>(
            ya, WvoT + (long)l * 768 * 768, bout + l * 768, x, ROWS, 768, 768, 768, 768, 0, 0, 0);
        // LN2
        ln_kernel<<<ROWS, 256, 0, stream>>>(x, ln2_g + l * 768, ln2_b + l * 768, yb);
        // h1 = gelu(y @ Wff1 + bff1)   [BN=128 2-buffer, launch_bounds(256,4)]
        gemm_bf16<128, 1, 0, 0, 0><<<dim3(24, 49, 1), 256, 0, stream>>>(
            yb, Wf1T + (long)l * 3072 * 768, bff1 + l * 3072, h1b, ROWS, 768, 768, 768, 3072, 0, 0, 0);
        // FF2 split-K=2 -> f32 partials P0,P1
        gemm_bf16<64, 0, 0, 1, 0><<<dim3(12, 49, 2), 256, 0, stream>>>(
            h1b, Wf2T + (long)l * 768 * 3072, nullptr, P0,
            ROWS, 1536, 3072, 3072, 768, 1536, 1536, (long)ROWS * DIMC);
        // zb = LN1_{l+1}(x + P0 + P1 + bff2)
        if (l < 5)
            combine_ln<0><<<ROWS, 256, 0, stream>>>(P0, P1, bff2 + l * 768, x,
                ln1_g + (l + 1) * 768, ln1_b + (l + 1) * 768, zb);
        else
            combine_ln<1><<<ROWS, 256, 0, stream>>>(P0, P1, bff2 + l * 768, x,
                ln1_g, ln1_b, zb);
    }

    // ---- final projection + un-patchify ----
    gemm_bf16<64, 0, 0, 1, 0><<<dim3(12, 49, 1), 256, 0, stream>>>(
        zb, WepT, bep, xe, ROWS, 768, 768, 768, 768, 0, 0, 0);
    unpatchify_kernel<<<(BATCH * 3 * 224 * 224 + 255) / 256, 256, 0, stream>>>(xe, out);
}